// Round 12
// baseline (386.702 us; speedup 1.0000x reference)
//
#include <hip/hip_runtime.h>
#include <math.h>

#define NN 50000
#define NE 60000
#define FIN 32
#define DIM 64
#define NGB 256   // graphs in batch

typedef short s8v __attribute__((ext_vector_type(8)));
typedef float f4v __attribute__((ext_vector_type(4)));

__device__ __forceinline__ float rl(float v, int lane) {
    return __int_as_float(__builtin_amdgcn_readlane(__float_as_int(v), lane));
}
__device__ __forceinline__ float sigm(float x) { return 1.f / (1.f + expf(-x)); }

// pack two f32 as bf16 (RTN-even) into one u32: a -> low16, b -> high16
__device__ __forceinline__ unsigned int pk2(float a, float b) {
    unsigned int ua = __float_as_uint(a);
    unsigned int ub = __float_as_uint(b);
    ua = (ua + 0x7FFFu + ((ua >> 16) & 1u)) >> 16;
    ub = (ub + 0x7FFFu + ((ub >> 16) & 1u)) & 0xFFFF0000u;
    return ua | ub;
}
__device__ __forceinline__ unsigned short pk1(float a) {
    unsigned int ua = __float_as_uint(a);
    return (unsigned short)((ua + 0x7FFFu + ((ua >> 16) & 1u)) >> 16);
}
__device__ __forceinline__ s8v as_s8(uint4 u) {
    union { uint4 a; s8v b; } c; c.a = u; return c.b;
}

// ---------------- precompute: W[i*64+o] = (relu(nn1_w + nn1_b) @ nn2_w^T + nn2_b)
__global__ void k_precompute_W(const float* __restrict__ nn1_w, const float* __restrict__ nn1_b,
                               const float* __restrict__ nn2_w, const float* __restrict__ nn2_b,
                               float* __restrict__ W) {
    __shared__ float t[64];
    int tid = threadIdx.x;
    if (tid < 64) t[tid] = fmaxf(nn1_w[tid] + nn1_b[tid], 0.f);
    __syncthreads();
    int k = blockIdx.x * blockDim.x + tid;   // 0..4095
    float acc = nn2_b[k];
    #pragma unroll
    for (int j = 0; j < 64; ++j) acc += t[j] * nn2_w[k * 64 + j];
    W[k] = acc;
}

// ---------------- pack weights into MFMA B-fragment layouts (bf16, XOR-swizzled)
__global__ void k_pack_mfma(const float* __restrict__ W, const float* __restrict__ wih,
                            const float* __restrict__ whh, const float* __restrict__ bih,
                            const float* __restrict__ bhh, unsigned int* __restrict__ P,
                            float* __restrict__ brz) {
    int q = blockIdx.x * 256 + threadIdx.x;   // 56*256 = 14336
    if (q < 128) brz[q] = bih[q] + bhh[q];    // summed r,z biases
    if (q < 2048) {                           // WpA
        int byte = q * 4, col = byte >> 7, rem = byte & 127;
        int lin = rem ^ ((col & 7) << 4);
        int k0 = (lin >> 4) * 8 + ((lin >> 2) & 3) * 2;
        P[q] = pk2(W[k0 * 64 + col], W[(k0 + 1) * 64 + col]);
    } else if (q < 10240) {                   // B01 (K=128)
        int w = q - 2048, byte = w * 4, col = byte >> 8, rem = byte & 255;
        int lin = rem ^ ((col & 7) << 4);
        int k0 = (lin >> 4) * 8 + ((lin >> 2) & 3) * 2;
        int g = col >> 6, o = col & 63;
        int rowbase = (g * 64 + o) * 64;
        const float* src = (k0 >= 64) ? whh : wih;
        int kk = (k0 >= 64) ? k0 - 64 : k0;
        P[q] = pk2(src[rowbase + kk], src[rowbase + kk + 1]);
    } else if (q < 12288) {                   // BnI
        int w = q - 10240, byte = w * 4, col = byte >> 7, rem = byte & 127;
        int lin = rem ^ ((col & 7) << 4);
        int k0 = (lin >> 4) * 8 + ((lin >> 2) & 3) * 2;
        P[q] = pk2(wih[(128 + col) * 64 + k0], wih[(128 + col) * 64 + k0 + 1]);
    } else {                                  // BnH
        int w = q - 12288, byte = w * 4, col = byte >> 7, rem = byte & 127;
        int lin = rem ^ ((col & 7) << 4);
        int k0 = (lin >> 4) * 8 + ((lin >> 2) & 3) * 2;
        P[q] = pk2(whh[(128 + col) * 64 + k0], whh[(128 + col) * 64 + k0 + 1]);
    }
}

// ---------------- transpose LSTM weights for coalesced gate dots
__global__ void k_transpose_lstm(const float* __restrict__ wih, const float* __restrict__ whh,
                                 float* __restrict__ wihT, float* __restrict__ whhT) {
    int p = blockIdx.x * 256 + threadIdx.x;
    if (p < 256 * 128) { int o = p >> 7, k = p & 127; wihT[k * 256 + o] = wih[p]; }
    if (p < 256 * 64)  { int o = p >> 6, k = p & 63;  whhT[k * 256 + o] = whh[p]; }
}

// ---------------- int degree over dst
__global__ void k_degi(const int* __restrict__ ei, int* __restrict__ degc) {
    int i = blockIdx.x * 256 + threadIdx.x;
    if (i < NE) atomicAdd(&degc[ei[NE + i]], 1);
}

// ---------------- exclusive scan of degc[NN] -> rowptr[NN+1], cursor copy
__global__ void __launch_bounds__(1024) k_scan50k(const int* __restrict__ degc,
                                                  int* __restrict__ rowptr,
                                                  int* __restrict__ cur) {
    __shared__ int part[1024];
    int t = threadIdx.x;
    const int CH = 49;                 // 1024*49 = 50176 >= NN
    int base = t * CH;
    int s = 0;
    for (int i = 0; i < CH; ++i) {
        int idx = base + i;
        if (idx < NN) s += degc[idx];
    }
    part[t] = s;
    __syncthreads();
    for (int off = 1; off < 1024; off <<= 1) {
        int v = (t >= off) ? part[t - off] : 0;
        __syncthreads();
        part[t] += v;
        __syncthreads();
    }
    int run = (t > 0) ? part[t - 1] : 0;   // exclusive prefix of this chunk
    for (int i = 0; i < CH; ++i) {
        int idx = base + i;
        if (idx < NN) {
            rowptr[idx] = run;
            cur[idx] = run;
            run += degc[idx];
        }
    }
    if (t == 1023) rowptr[NN] = part[1023];
}

// ---------------- fill CSR adjacency: adj[pos] = src for each (src,dst) edge
__global__ void k_fill(const int* __restrict__ ei, int* __restrict__ cur,
                       int* __restrict__ adj) {
    int i = blockIdx.x * 256 + threadIdx.x;
    if (i < NE) {
        int s = ei[i], d = ei[NE + i];
        int pos = atomicAdd(&cur[d], 1);
        adj[pos] = s;
    }
}

// ---------------- per-graph starts/cnt via binary search on sorted batch (no atomics)
__global__ void k_bounds(const int* __restrict__ batch, int* __restrict__ starts,
                         int* __restrict__ cnt) {
    __shared__ int sLB[257];
    int b = threadIdx.x;   // 0..255
    int lo = 0, hi = NN;
    while (lo < hi) {      // lower_bound(batch, b)
        int mid = (lo + hi) >> 1;
        if (batch[mid] < b) lo = mid + 1; else hi = mid;
    }
    sLB[b] = lo;
    if (b == 0) sLB[256] = NN;
    __syncthreads();
    starts[b] = sLB[b];
    cnt[b] = sLB[b + 1] - sLB[b];
}

// ---------------- lin0: h = relu(x @ lin0_w^T + b); grid-stride, weights staged ONCE
__global__ void k_lin0(const float* __restrict__ x, const float* __restrict__ w,
                       const float* __restrict__ b, float* __restrict__ h) {
    __shared__ float wT[FIN * 64];   // wT[k*64+o] = w[o*32+k]
    int tid = threadIdx.x;
    for (int p = tid; p < FIN * 64; p += 256) {
        int k = p >> 6, o = p & 63;          // linear LDS write, strided L2-hit read
        wT[p] = w[o * FIN + k];
    }
    __syncthreads();
    int l = tid & 63;
    float bl = b[l];
    int wave = blockIdx.x * 4 + (tid >> 6);
    int nwaves = gridDim.x * 4;
    for (int n0 = wave * 2; n0 < NN; n0 += nwaves * 2) {   // NN even: both nodes valid
        float xv0 = x[n0 * FIN + (l & 31)];
        float xv1 = x[(n0 + 1) * FIN + (l & 31)];
        float a0 = bl, a1 = bl;
        #pragma unroll
        for (int k = 0; k < FIN; ++k) {
            float wk = wT[k * 64 + l];
            a0 += rl(xv0, k) * wk;
            a1 += rl(xv1, k) * wk;
        }
        h[n0 * 64 + l] = fmaxf(a0, 0.f);
        h[(n0 + 1) * 64 + l] = fmaxf(a1, 0.f);
    }
}

// ---------------- CSR gather: agg[n] = sum of h[src] over in-edges (no atomics)
// thread = (node, 16B chunk); 16 consecutive threads read each src row coalesced.
__global__ void __launch_bounds__(256) k_gather(const int* __restrict__ rowptr,
                                                const int* __restrict__ adj,
                                                const float* __restrict__ h,
                                                float* __restrict__ agg) {
    int gid = blockIdx.x * 256 + threadIdx.x;   // n*16 + c
    if (gid >= NN * 16) return;
    int n = gid >> 4, c = gid & 15;
    int s = rowptr[n], e = rowptr[n + 1];
    float4 acc = {0.f, 0.f, 0.f, 0.f};
    for (int k = s; k < e; ++k) {
        int src = adj[k];
        float4 v = *(const float4*)(h + src * 64 + c * 4);
        acc.x += v.x; acc.y += v.y; acc.z += v.z; acc.w += v.w;
    }
    *(float4*)(agg + n * 64 + c * 4) = acc;
}

// ---------------- MFMA conv(W)+GRU node update. Wave = 16 nodes, block = 4 waves.
// LDS: 56 KB pre-packed bf16 weights (straight copy) + 4 x 2 KB per-wave m-transpose.
__global__ void __launch_bounds__(256) k_update(
    const float* __restrict__ agg, const int* __restrict__ rowptr,
    const unsigned int* __restrict__ P, const float* __restrict__ conv_b,
    const float* __restrict__ brz, const float* __restrict__ bih, const float* __restrict__ bhh,
    float* __restrict__ h) {
    __shared__ unsigned int L[16384];   // 64 KB
    int tid = threadIdx.x;
    #pragma unroll
    for (int p = 0; p < 14336; p += 256) L[p + tid] = P[p + tid];
    __syncthreads();

    int l = tid & 63;
    int w = tid >> 6;
    int nb = (blockIdx.x * 4 + w) * 16;
    if (nb >= NN) return;               // idle waves in last block (after barrier)
    int row = l & 15, kq = l >> 4;      // A/B frag: row/col = lane&15, k-chunk = lane>>4
    int node = nb + row;

    float dv = (float)(rowptr[node + 1] - rowptr[node]);
    float inv = dv > 0.f ? 1.f / dv : 0.f;

    // ---- A-frags of agg_mean (bf16)
    uint4 aA[2];
    #pragma unroll
    for (int kt = 0; kt < 2; ++kt) {
        const float4* src = (const float4*)(agg + node * 64 + kt * 32 + kq * 8);
        float4 x0 = src[0], x1 = src[1];
        aA[kt].x = pk2(x0.x * inv, x0.y * inv);
        aA[kt].y = pk2(x0.z * inv, x0.w * inv);
        aA[kt].z = pk2(x1.x * inv, x1.y * inv);
        aA[kt].w = pk2(x1.z * inv, x1.w * inv);
    }

    // ---- stage A: m = relu(aggmean @ W + conv_b)
    f4v mC[4];
    #pragma unroll
    for (int ct = 0; ct < 4; ++ct) {
        f4v acc = {0.f, 0.f, 0.f, 0.f};
        int col = ct * 16 + row;
        #pragma unroll
        for (int kt = 0; kt < 2; ++kt) {
            int boff = col * 128 + ((kt * 64 + kq * 16) ^ ((col & 7) << 4));
            uint4 b = *(const uint4*)((const char*)L + boff);
            acc = __builtin_amdgcn_mfma_f32_16x16x32_bf16(as_s8(aA[kt]), as_s8(b), acc, 0, 0, 0);
        }
        mC[ct] = acc;
    }

    // ---- transpose m to A-frag layout via per-wave LDS region (swizzled)
    int mbase = 57344 + w * 2048;
    #pragma unroll
    for (int ct = 0; ct < 4; ++ct) {
        int ch = ct * 16 + row;
        float cb = conv_b[ch];
        #pragma unroll
        for (int r = 0; r < 4; ++r) {
            float mval = fmaxf(mC[ct][r] + cb, 0.f);
            int nrow = kq * 4 + r;
            int off = mbase + ((nrow * 128 + ch * 2) ^ ((nrow & 7) << 4));
            *(unsigned short*)((char*)L + off) = pk1(mval);
        }
    }
    // same-wave DS ordering: reads below see the writes above (no block barrier needed)
    uint4 mA[2], hA[2];
    #pragma unroll
    for (int kt = 0; kt < 2; ++kt) {
        int off = mbase + ((row * 128 + kt * 64 + kq * 16) ^ ((row & 7) << 4));
        mA[kt] = *(const uint4*)((const char*)L + off);
        const float4* hs = (const float4*)(h + node * 64 + kt * 32 + kq * 8);
        float4 y0 = hs[0], y1 = hs[1];
        hA[kt].x = pk2(y0.x, y0.y);
        hA[kt].y = pk2(y0.z, y0.w);
        hA[kt].z = pk2(y1.x, y1.y);
        hA[kt].w = pk2(y1.z, y1.w);
    }

    // ---- gates r,z: [m|h](16x128) @ B01(128x128)
    f4v g01[8];
    #pragma unroll
    for (int ct = 0; ct < 8; ++ct) {
        f4v acc = {0.f, 0.f, 0.f, 0.f};
        int col = ct * 16 + row;
        #pragma unroll
        for (int kt = 0; kt < 4; ++kt) {
            uint4 a = (kt < 2) ? mA[kt] : hA[kt - 2];
            int boff = 8192 + col * 256 + ((kt * 64 + kq * 16) ^ ((col & 7) << 4));
            uint4 b = *(const uint4*)((const char*)L + boff);
            acc = __builtin_amdgcn_mfma_f32_16x16x32_bf16(as_s8(a), as_s8(b), acc, 0, 0, 0);
        }
        g01[ct] = acc;
    }
    // ---- i_n = m @ wih_n^T ; h_n = h @ whh_n^T
    f4v gin[4], ghn[4];
    #pragma unroll
    for (int ct = 0; ct < 4; ++ct) {
        f4v ai = {0.f, 0.f, 0.f, 0.f}, ah = {0.f, 0.f, 0.f, 0.f};
        int col = ct * 16 + row;
        #pragma unroll
        for (int kt = 0; kt < 2; ++kt) {
            int swz = (kt * 64 + kq * 16) ^ ((col & 7) << 4);
            uint4 bi = *(const uint4*)((const char*)L + 40960 + col * 128 + swz);
            uint4 bh = *(const uint4*)((const char*)L + 49152 + col * 128 + swz);
            ai = __builtin_amdgcn_mfma_f32_16x16x32_bf16(as_s8(mA[kt]), as_s8(bi), ai, 0, 0, 0);
            ah = __builtin_amdgcn_mfma_f32_16x16x32_bf16(as_s8(hA[kt]), as_s8(bh), ah, 0, 0, 0);
        }
        gin[ct] = ai; ghn[ct] = ah;
    }

    // ---- epilogue: GRU cell in C-frag layout (col=lane&15, row=(lane>>4)*4+r)
    #pragma unroll
    for (int ct = 0; ct < 4; ++ct) {
        int ch = ct * 16 + row;
        float br = brz[ch], bz = brz[64 + ch];
        float bin = bih[128 + ch], bhn = bhh[128 + ch];
        #pragma unroll
        for (int r = 0; r < 4; ++r) {
            int n2 = nb + kq * 4 + r;
            float rg = sigm(g01[ct][r] + br);
            float zg = sigm(g01[4 + ct][r] + bz);
            float ng = tanhf(gin[ct][r] + bin + rg * (ghn[ct][r] + bhn));
            float hold = h[n2 * 64 + ch];
            h[n2 * 64 + ch] = (1.f - zg) * ng + zg * hold;
        }
    }
}

// ---------------- fused Set2Set step: LSTM + ONLINE segment softmax + weighted sum.
__global__ void __launch_bounds__(1024) k_s2s(
    const float* __restrict__ h, const int* __restrict__ starts,
    const int* __restrict__ cnt, const float* __restrict__ wihT,
    const float* __restrict__ whhT, const float* __restrict__ bih,
    const float* __restrict__ bhh, float* __restrict__ hl,
    float* __restrict__ cl, float* __restrict__ qstar, int first) {
    __shared__ float ga[256];
    __shared__ float hlv[64];
    __shared__ float mw[16], ssw[16];
    __shared__ float accw[16][64];
    int b = blockIdx.x, tid = threadIdx.x, w = tid >> 6, l = tid & 63;

    if (first) {
        if (tid < 64) {   // q_star = 0, hl = 0, cl = 0 -> gates are biases only
            float ig = sigm(bih[tid] + bhh[tid]);
            float gg = tanhf(bih[128 + tid] + bhh[128 + tid]);
            float og = sigm(bih[192 + tid] + bhh[192 + tid]);
            float c = ig * gg;
            cl[b * 64 + tid] = c;
            float hh = og * tanhf(c);
            hl[b * 64 + tid] = hh;
            hlv[tid] = hh;
        }
    } else {
        if (tid < 256) {
            const float* qs = qstar + b * 128;
            const float* hb = hl + b * 64;
            float a = bih[tid] + bhh[tid];
            for (int k = 0; k < 128; ++k) a += qs[k] * wihT[k * 256 + tid];
            for (int k = 0; k < 64; ++k)  a += hb[k] * whhT[k * 256 + tid];
            ga[tid] = a;
        }
        __syncthreads();
        if (tid < 64) {
            float c = sigm(ga[64 + tid]) * cl[b * 64 + tid] + sigm(ga[tid]) * tanhf(ga[128 + tid]);
            cl[b * 64 + tid] = c;
            float hh = sigm(ga[192 + tid]) * tanhf(c);
            hl[b * 64 + tid] = hh;
            hlv[tid] = hh;
        }
    }
    __syncthreads();

    int s = starts[b], c = cnt[b];
    float hld = hlv[l];
    float m = -1e30f, ss = 0.f, racc = 0.f;
    for (int i = w; i < c; i += 16) {
        float hv = h[(s + i) * 64 + l];
        float v = hv * hld;
        #pragma unroll
        for (int off = 32; off; off >>= 1) v += __shfl_xor(v, off, 64);
        float nm = fmaxf(m, v);
        float scale = expf(m - nm);     // 0 on first hit, 1 if no new max
        float p = expf(v - nm);
        ss = ss * scale + p;
        racc = racc * scale + p * hv;
        m = nm;
    }
    if (l == 0) { mw[w] = m; ssw[w] = ss; }
    accw[w][l] = racc;
    __syncthreads();
    if (tid < 64) {
        float M = -1e30f;
        #pragma unroll
        for (int q = 0; q < 16; ++q) M = fmaxf(M, mw[q]);
        float asum = 0.f, r = 0.f;
        #pragma unroll
        for (int q = 0; q < 16; ++q) {
            float f = expf(mw[q] - M);   // 0 for empty waves when M finite
            asum += ssw[q] * f;
            r += accw[q][tid] * f;
        }
        qstar[b * 128 + tid] = hlv[tid];
        qstar[b * 128 + 64 + tid] = r / (asum + 1e-16f);
    }
}

extern "C" void kernel_launch(void* const* d_in, const int* in_sizes, int n_in,
                              void* d_out, int out_size, void* d_ws, size_t ws_size,
                              hipStream_t stream) {
    const float* x      = (const float*)d_in[0];
    const int*   ei     = (const int*)  d_in[1];
    const int*   batch  = (const int*)  d_in[2];
    const float* lin0_w = (const float*)d_in[3];
    const float* lin0_b = (const float*)d_in[4];
    const float* nn1_w  = (const float*)d_in[5];
    const float* nn1_b  = (const float*)d_in[6];
    const float* nn2_w  = (const float*)d_in[7];
    const float* nn2_b  = (const float*)d_in[8];
    const float* conv_b = (const float*)d_in[9];
    const float* gwih   = (const float*)d_in[10];
    const float* gwhh   = (const float*)d_in[11];
    const float* gbih   = (const float*)d_in[12];
    const float* gbhh   = (const float*)d_in[13];
    const float* lwih   = (const float*)d_in[14];
    const float* lwhh   = (const float*)d_in[15];
    const float* lbih   = (const float*)d_in[16];
    const float* lbhh   = (const float*)d_in[17];

    float* qstar = (float*)d_out;                 // [256*128]
    float* h     = (float*)d_out + NGB * 128;     // [N*64] == feat_map

    float* ws     = (float*)d_ws;
    float* W      = ws;                         // 4096
    float* agg    = ws + 4096;                  // N*64
    int*   rowptr = (int*)(agg + NN * 64);      // NN+1
    int*   curp   = rowptr + NN + 1;            // NN
    int*   adj    = curp + NN;                  // NE
    int*   degc   = adj + NE;                   // NN
    int*   cnt    = degc + NN;                  // 256
    int*   starts = cnt + 256;                  // 256
    float* hl     = (float*)(starts + 256);     // 256*64
    float* cl     = hl + NGB * 64;              // 256*64
    float* wihT   = cl + NGB * 64;              // 128*256
    float* whhT   = wihT + 128 * 256;           // 64*256
    unsigned int* P = (unsigned int*)(whhT + 64 * 256);  // 14336
    float* brz    = (float*)(P + 14336);        // 128

    hipMemsetAsync(degc, 0, NN * sizeof(int), stream);

    k_precompute_W<<<16, 256, 0, stream>>>(nn1_w, nn1_b, nn2_w, nn2_b, W);
    k_pack_mfma<<<56, 256, 0, stream>>>(W, gwih, gwhh, gbih, gbhh, P, brz);
    k_transpose_lstm<<<128, 256, 0, stream>>>(lwih, lwhh, wihT, whhT);
    k_degi<<<(NE + 255) / 256, 256, 0, stream>>>(ei, degc);
    k_scan50k<<<1, 1024, 0, stream>>>(degc, rowptr, curp);
    k_fill<<<(NE + 255) / 256, 256, 0, stream>>>(ei, curp, adj);
    k_bounds<<<1, 256, 0, stream>>>(batch, starts, cnt);
    k_lin0<<<512, 256, 0, stream>>>(x, lin0_w, lin0_b, h);

    for (int it = 0; it < 3; ++it) {
        k_gather<<<(NN * 16 + 255) / 256, 256, 0, stream>>>(rowptr, adj, h, agg);
        k_update<<<782, 256, 0, stream>>>(agg, rowptr, P, conv_b, brz, gbih, gbhh, h);
    }
    for (int st = 0; st < 3; ++st) {
        k_s2s<<<NGB, 1024, 0, stream>>>(h, starts, cnt, wihT, whhT, lbih, lbhh,
                                        hl, cl, qstar, st == 0 ? 1 : 0);
    }
}

// Round 13
// 270.255 us; speedup vs baseline: 1.4309x; 1.4309x over previous
//
#include <hip/hip_runtime.h>
#include <math.h>

#define NN 50000
#define NE 60000
#define FIN 32
#define DIM 64
#define NGB 256   // graphs in batch
#define SCB 196   // scan blocks: 196*256 = 50176 >= NN

typedef short s8v __attribute__((ext_vector_type(8)));
typedef float f4v __attribute__((ext_vector_type(4)));

__device__ __forceinline__ float rl(float v, int lane) {
    return __int_as_float(__builtin_amdgcn_readlane(__float_as_int(v), lane));
}
__device__ __forceinline__ float sigm(float x) { return 1.f / (1.f + expf(-x)); }

// pack two f32 as bf16 (RTN-even) into one u32: a -> low16, b -> high16
__device__ __forceinline__ unsigned int pk2(float a, float b) {
    unsigned int ua = __float_as_uint(a);
    unsigned int ub = __float_as_uint(b);
    ua = (ua + 0x7FFFu + ((ua >> 16) & 1u)) >> 16;
    ub = (ub + 0x7FFFu + ((ub >> 16) & 1u)) & 0xFFFF0000u;
    return ua | ub;
}
__device__ __forceinline__ unsigned short pk1(float a) {
    unsigned int ua = __float_as_uint(a);
    return (unsigned short)((ua + 0x7FFFu + ((ua >> 16) & 1u)) >> 16);
}
__device__ __forceinline__ s8v as_s8(uint4 u) {
    union { uint4 a; s8v b; } c; c.a = u; return c.b;
}

// ---------------- precompute: W[i*64+o] = (relu(nn1_w + nn1_b) @ nn2_w^T + nn2_b)
__global__ void k_precompute_W(const float* __restrict__ nn1_w, const float* __restrict__ nn1_b,
                               const float* __restrict__ nn2_w, const float* __restrict__ nn2_b,
                               float* __restrict__ W) {
    __shared__ float t[64];
    int tid = threadIdx.x;
    if (tid < 64) t[tid] = fmaxf(nn1_w[tid] + nn1_b[tid], 0.f);
    __syncthreads();
    int k = blockIdx.x * blockDim.x + tid;   // 0..4095
    float acc = nn2_b[k];
    #pragma unroll
    for (int j = 0; j < 64; ++j) acc += t[j] * nn2_w[k * 64 + j];
    W[k] = acc;
}

// ---------------- pack weights into MFMA B-fragment layouts (bf16, XOR-swizzled)
__global__ void k_pack_mfma(const float* __restrict__ W, const float* __restrict__ wih,
                            const float* __restrict__ whh, const float* __restrict__ bih,
                            const float* __restrict__ bhh, unsigned int* __restrict__ P,
                            float* __restrict__ brz) {
    int q = blockIdx.x * 256 + threadIdx.x;   // 56*256 = 14336
    if (q < 128) brz[q] = bih[q] + bhh[q];    // summed r,z biases
    if (q < 2048) {                           // WpA
        int byte = q * 4, col = byte >> 7, rem = byte & 127;
        int lin = rem ^ ((col & 7) << 4);
        int k0 = (lin >> 4) * 8 + ((lin >> 2) & 3) * 2;
        P[q] = pk2(W[k0 * 64 + col], W[(k0 + 1) * 64 + col]);
    } else if (q < 10240) {                   // B01 (K=128)
        int w = q - 2048, byte = w * 4, col = byte >> 8, rem = byte & 255;
        int lin = rem ^ ((col & 7) << 4);
        int k0 = (lin >> 4) * 8 + ((lin >> 2) & 3) * 2;
        int g = col >> 6, o = col & 63;
        int rowbase = (g * 64 + o) * 64;
        const float* src = (k0 >= 64) ? whh : wih;
        int kk = (k0 >= 64) ? k0 - 64 : k0;
        P[q] = pk2(src[rowbase + kk], src[rowbase + kk + 1]);
    } else if (q < 12288) {                   // BnI
        int w = q - 10240, byte = w * 4, col = byte >> 7, rem = byte & 127;
        int lin = rem ^ ((col & 7) << 4);
        int k0 = (lin >> 4) * 8 + ((lin >> 2) & 3) * 2;
        P[q] = pk2(wih[(128 + col) * 64 + k0], wih[(128 + col) * 64 + k0 + 1]);
    } else {                                  // BnH
        int w = q - 12288, byte = w * 4, col = byte >> 7, rem = byte & 127;
        int lin = rem ^ ((col & 7) << 4);
        int k0 = (lin >> 4) * 8 + ((lin >> 2) & 3) * 2;
        P[q] = pk2(whh[(128 + col) * 64 + k0], whh[(128 + col) * 64 + k0 + 1]);
    }
}

// ---------------- transpose LSTM weights for coalesced gate dots
__global__ void k_transpose_lstm(const float* __restrict__ wih, const float* __restrict__ whh,
                                 float* __restrict__ wihT, float* __restrict__ whhT) {
    int p = blockIdx.x * 256 + threadIdx.x;
    if (p < 256 * 128) { int o = p >> 7, k = p & 127; wihT[k * 256 + o] = wih[p]; }
    if (p < 256 * 64)  { int o = p >> 6, k = p & 63;  whhT[k * 256 + o] = whh[p]; }
}

// ---------------- int degree over dst
__global__ void k_degi(const int* __restrict__ ei, int* __restrict__ degc) {
    int i = blockIdx.x * 256 + threadIdx.x;
    if (i < NE) atomicAdd(&degc[ei[NE + i]], 1);
}

// ---------------- hierarchical scan, level 1: per-block sums of degc
__global__ void k_bsum(const int* __restrict__ degc, int* __restrict__ bsum) {
    __shared__ int red[256];
    int t = threadIdx.x;
    int idx = blockIdx.x * 256 + t;
    red[t] = (idx < NN) ? degc[idx] : 0;
    __syncthreads();
    for (int off = 128; off; off >>= 1) {
        if (t < off) red[t] += red[t + off];
        __syncthreads();
    }
    if (t == 0) bsum[blockIdx.x] = red[0];
}

// ---------------- hierarchical scan, level 2: block offset + local scan -> rowptr, cur
__global__ void k_emit(const int* __restrict__ degc, const int* __restrict__ bsum,
                       int* __restrict__ rowptr, int* __restrict__ cur) {
    __shared__ int bo[256];
    __shared__ int sc[256];
    int t = threadIdx.x;
    int idx = blockIdx.x * 256 + t;
    bo[t] = (t < blockIdx.x) ? bsum[t] : 0;   // blockIdx.x <= 195 < 256
    __syncthreads();
    for (int off = 128; off; off >>= 1) {
        if (t < off) bo[t] += bo[t + off];
        __syncthreads();
    }
    int boff = bo[0];
    int v = (idx < NN) ? degc[idx] : 0;
    sc[t] = v;
    __syncthreads();
    for (int off = 1; off < 256; off <<= 1) {   // inclusive scan
        int u = (t >= off) ? sc[t - off] : 0;
        __syncthreads();
        sc[t] += u;
        __syncthreads();
    }
    if (idx <= NN) {
        int excl = boff + sc[t] - v;   // for idx==NN: v=0, sc = block total -> grand total
        rowptr[idx] = excl;
        if (idx < NN) cur[idx] = excl;
    }
}

// ---------------- fill CSR adjacency: adj[pos] = src for each (src,dst) edge
__global__ void k_fill(const int* __restrict__ ei, int* __restrict__ cur,
                       int* __restrict__ adj) {
    int i = blockIdx.x * 256 + threadIdx.x;
    if (i < NE) {
        int s = ei[i], d = ei[NE + i];
        int pos = atomicAdd(&cur[d], 1);
        adj[pos] = s;
    }
}

// ---------------- per-graph starts/cnt via binary search on sorted batch (no atomics)
__global__ void k_bounds(const int* __restrict__ batch, int* __restrict__ starts,
                         int* __restrict__ cnt) {
    __shared__ int sLB[257];
    int b = threadIdx.x;   // 0..255
    int lo = 0, hi = NN;
    while (lo < hi) {      // lower_bound(batch, b)
        int mid = (lo + hi) >> 1;
        if (batch[mid] < b) lo = mid + 1; else hi = mid;
    }
    sLB[b] = lo;
    if (b == 0) sLB[256] = NN;
    __syncthreads();
    starts[b] = sLB[b];
    cnt[b] = sLB[b + 1] - sLB[b];
}

// ---------------- lin0: h = relu(x @ lin0_w^T + b); grid-stride, weights staged ONCE
__global__ void k_lin0(const float* __restrict__ x, const float* __restrict__ w,
                       const float* __restrict__ b, float* __restrict__ h) {
    __shared__ float wT[FIN * 64];   // wT[k*64+o] = w[o*32+k]
    int tid = threadIdx.x;
    for (int p = tid; p < FIN * 64; p += 256) {
        int k = p >> 6, o = p & 63;          // linear LDS write, strided L2-hit read
        wT[p] = w[o * FIN + k];
    }
    __syncthreads();
    int l = tid & 63;
    float bl = b[l];
    int wave = blockIdx.x * 4 + (tid >> 6);
    int nwaves = gridDim.x * 4;
    for (int n0 = wave * 2; n0 < NN; n0 += nwaves * 2) {   // NN even: both nodes valid
        float xv0 = x[n0 * FIN + (l & 31)];
        float xv1 = x[(n0 + 1) * FIN + (l & 31)];
        float a0 = bl, a1 = bl;
        #pragma unroll
        for (int k = 0; k < FIN; ++k) {
            float wk = wT[k * 64 + l];
            a0 += rl(xv0, k) * wk;
            a1 += rl(xv1, k) * wk;
        }
        h[n0 * 64 + l] = fmaxf(a0, 0.f);
        h[(n0 + 1) * 64 + l] = fmaxf(a1, 0.f);
    }
}

// ---------------- CSR gather: agg[n] = sum of h[src] over in-edges (no atomics)
__global__ void __launch_bounds__(256) k_gather(const int* __restrict__ rowptr,
                                                const int* __restrict__ adj,
                                                const float* __restrict__ h,
                                                float* __restrict__ agg) {
    int gid = blockIdx.x * 256 + threadIdx.x;   // n*16 + c
    if (gid >= NN * 16) return;
    int n = gid >> 4, c = gid & 15;
    int s = rowptr[n], e = rowptr[n + 1];
    float4 acc = {0.f, 0.f, 0.f, 0.f};
    for (int k = s; k < e; ++k) {
        int src = adj[k];
        float4 v = *(const float4*)(h + src * 64 + c * 4);
        acc.x += v.x; acc.y += v.y; acc.z += v.z; acc.w += v.w;
    }
    *(float4*)(agg + n * 64 + c * 4) = acc;
}

// ---------------- MFMA conv(W)+GRU node update. Wave = 16 nodes, block = 4 waves.
__global__ void __launch_bounds__(256) k_update(
    const float* __restrict__ agg, const int* __restrict__ rowptr,
    const unsigned int* __restrict__ P, const float* __restrict__ conv_b,
    const float* __restrict__ brz, const float* __restrict__ bih, const float* __restrict__ bhh,
    float* __restrict__ h) {
    __shared__ unsigned int L[16384];   // 64 KB
    int tid = threadIdx.x;
    #pragma unroll
    for (int p = 0; p < 14336; p += 256) L[p + tid] = P[p + tid];
    __syncthreads();

    int l = tid & 63;
    int w = tid >> 6;
    int nb = (blockIdx.x * 4 + w) * 16;
    if (nb >= NN) return;               // idle waves in last block (after barrier)
    int row = l & 15, kq = l >> 4;      // A/B frag: row/col = lane&15, k-chunk = lane>>4
    int node = nb + row;

    float dv = (float)(rowptr[node + 1] - rowptr[node]);
    float inv = dv > 0.f ? 1.f / dv : 0.f;

    // ---- A-frags of agg_mean (bf16)
    uint4 aA[2];
    #pragma unroll
    for (int kt = 0; kt < 2; ++kt) {
        const float4* src = (const float4*)(agg + node * 64 + kt * 32 + kq * 8);
        float4 x0 = src[0], x1 = src[1];
        aA[kt].x = pk2(x0.x * inv, x0.y * inv);
        aA[kt].y = pk2(x0.z * inv, x0.w * inv);
        aA[kt].z = pk2(x1.x * inv, x1.y * inv);
        aA[kt].w = pk2(x1.z * inv, x1.w * inv);
    }

    // ---- stage A: m = relu(aggmean @ W + conv_b)
    f4v mC[4];
    #pragma unroll
    for (int ct = 0; ct < 4; ++ct) {
        f4v acc = {0.f, 0.f, 0.f, 0.f};
        int col = ct * 16 + row;
        #pragma unroll
        for (int kt = 0; kt < 2; ++kt) {
            int boff = col * 128 + ((kt * 64 + kq * 16) ^ ((col & 7) << 4));
            uint4 b = *(const uint4*)((const char*)L + boff);
            acc = __builtin_amdgcn_mfma_f32_16x16x32_bf16(as_s8(aA[kt]), as_s8(b), acc, 0, 0, 0);
        }
        mC[ct] = acc;
    }

    // ---- transpose m to A-frag layout via per-wave LDS region (swizzled)
    int mbase = 57344 + w * 2048;
    #pragma unroll
    for (int ct = 0; ct < 4; ++ct) {
        int ch = ct * 16 + row;
        float cb = conv_b[ch];
        #pragma unroll
        for (int r = 0; r < 4; ++r) {
            float mval = fmaxf(mC[ct][r] + cb, 0.f);
            int nrow = kq * 4 + r;
            int off = mbase + ((nrow * 128 + ch * 2) ^ ((nrow & 7) << 4));
            *(unsigned short*)((char*)L + off) = pk1(mval);
        }
    }
    // same-wave DS ordering: reads below see the writes above (no block barrier needed)
    uint4 mA[2], hA[2];
    #pragma unroll
    for (int kt = 0; kt < 2; ++kt) {
        int off = mbase + ((row * 128 + kt * 64 + kq * 16) ^ ((row & 7) << 4));
        mA[kt] = *(const uint4*)((const char*)L + off);
        const float4* hs = (const float4*)(h + node * 64 + kt * 32 + kq * 8);
        float4 y0 = hs[0], y1 = hs[1];
        hA[kt].x = pk2(y0.x, y0.y);
        hA[kt].y = pk2(y0.z, y0.w);
        hA[kt].z = pk2(y1.x, y1.y);
        hA[kt].w = pk2(y1.z, y1.w);
    }

    // ---- gates r,z: [m|h](16x128) @ B01(128x128)
    f4v g01[8];
    #pragma unroll
    for (int ct = 0; ct < 8; ++ct) {
        f4v acc = {0.f, 0.f, 0.f, 0.f};
        int col = ct * 16 + row;
        #pragma unroll
        for (int kt = 0; kt < 4; ++kt) {
            uint4 a = (kt < 2) ? mA[kt] : hA[kt - 2];
            int boff = 8192 + col * 256 + ((kt * 64 + kq * 16) ^ ((col & 7) << 4));
            uint4 b = *(const uint4*)((const char*)L + boff);
            acc = __builtin_amdgcn_mfma_f32_16x16x32_bf16(as_s8(a), as_s8(b), acc, 0, 0, 0);
        }
        g01[ct] = acc;
    }
    // ---- i_n = m @ wih_n^T ; h_n = h @ whh_n^T
    f4v gin[4], ghn[4];
    #pragma unroll
    for (int ct = 0; ct < 4; ++ct) {
        f4v ai = {0.f, 0.f, 0.f, 0.f}, ah = {0.f, 0.f, 0.f, 0.f};
        int col = ct * 16 + row;
        #pragma unroll
        for (int kt = 0; kt < 2; ++kt) {
            int swz = (kt * 64 + kq * 16) ^ ((col & 7) << 4);
            uint4 bi = *(const uint4*)((const char*)L + 40960 + col * 128 + swz);
            uint4 bh = *(const uint4*)((const char*)L + 49152 + col * 128 + swz);
            ai = __builtin_amdgcn_mfma_f32_16x16x32_bf16(as_s8(mA[kt]), as_s8(bi), ai, 0, 0, 0);
            ah = __builtin_amdgcn_mfma_f32_16x16x32_bf16(as_s8(hA[kt]), as_s8(bh), ah, 0, 0, 0);
        }
        gin[ct] = ai; ghn[ct] = ah;
    }

    // ---- epilogue: GRU cell in C-frag layout (col=lane&15, row=(lane>>4)*4+r)
    #pragma unroll
    for (int ct = 0; ct < 4; ++ct) {
        int ch = ct * 16 + row;
        float br = brz[ch], bz = brz[64 + ch];
        float bin = bih[128 + ch], bhn = bhh[128 + ch];
        #pragma unroll
        for (int r = 0; r < 4; ++r) {
            int n2 = nb + kq * 4 + r;
            float rg = sigm(g01[ct][r] + br);
            float zg = sigm(g01[4 + ct][r] + bz);
            float ng = tanhf(gin[ct][r] + bin + rg * (ghn[ct][r] + bhn));
            float hold = h[n2 * 64 + ch];
            h[n2 * 64 + ch] = (1.f - zg) * ng + zg * hold;
        }
    }
}

// ---------------- fused Set2Set step: LSTM + ONLINE segment softmax + weighted sum.
__global__ void __launch_bounds__(1024) k_s2s(
    const float* __restrict__ h, const int* __restrict__ starts,
    const int* __restrict__ cnt, const float* __restrict__ wihT,
    const float* __restrict__ whhT, const float* __restrict__ bih,
    const float* __restrict__ bhh, float* __restrict__ hl,
    float* __restrict__ cl, float* __restrict__ qstar, int first) {
    __shared__ float ga[256];
    __shared__ float hlv[64];
    __shared__ float mw[16], ssw[16];
    __shared__ float accw[16][64];
    int b = blockIdx.x, tid = threadIdx.x, w = tid >> 6, l = tid & 63;

    if (first) {
        if (tid < 64) {   // q_star = 0, hl = 0, cl = 0 -> gates are biases only
            float ig = sigm(bih[tid] + bhh[tid]);
            float gg = tanhf(bih[128 + tid] + bhh[128 + tid]);
            float og = sigm(bih[192 + tid] + bhh[192 + tid]);
            float c = ig * gg;
            cl[b * 64 + tid] = c;
            float hh = og * tanhf(c);
            hl[b * 64 + tid] = hh;
            hlv[tid] = hh;
        }
    } else {
        if (tid < 256) {
            const float* qs = qstar + b * 128;
            const float* hb = hl + b * 64;
            float a = bih[tid] + bhh[tid];
            for (int k = 0; k < 128; ++k) a += qs[k] * wihT[k * 256 + tid];
            for (int k = 0; k < 64; ++k)  a += hb[k] * whhT[k * 256 + tid];
            ga[tid] = a;
        }
        __syncthreads();
        if (tid < 64) {
            float c = sigm(ga[64 + tid]) * cl[b * 64 + tid] + sigm(ga[tid]) * tanhf(ga[128 + tid]);
            cl[b * 64 + tid] = c;
            float hh = sigm(ga[192 + tid]) * tanhf(c);
            hl[b * 64 + tid] = hh;
            hlv[tid] = hh;
        }
    }
    __syncthreads();

    int s = starts[b], c = cnt[b];
    float hld = hlv[l];
    float m = -1e30f, ss = 0.f, racc = 0.f;
    for (int i = w; i < c; i += 16) {
        float hv = h[(s + i) * 64 + l];
        float v = hv * hld;
        #pragma unroll
        for (int off = 32; off; off >>= 1) v += __shfl_xor(v, off, 64);
        float nm = fmaxf(m, v);
        float scale = expf(m - nm);     // 0 on first hit, 1 if no new max
        float p = expf(v - nm);
        ss = ss * scale + p;
        racc = racc * scale + p * hv;
        m = nm;
    }
    if (l == 0) { mw[w] = m; ssw[w] = ss; }
    accw[w][l] = racc;
    __syncthreads();
    if (tid < 64) {
        float M = -1e30f;
        #pragma unroll
        for (int q = 0; q < 16; ++q) M = fmaxf(M, mw[q]);
        float asum = 0.f, r = 0.f;
        #pragma unroll
        for (int q = 0; q < 16; ++q) {
            float f = expf(mw[q] - M);   // 0 for empty waves when M finite
            asum += ssw[q] * f;
            r += accw[q][tid] * f;
        }
        qstar[b * 128 + tid] = hlv[tid];
        qstar[b * 128 + 64 + tid] = r / (asum + 1e-16f);
    }
}

extern "C" void kernel_launch(void* const* d_in, const int* in_sizes, int n_in,
                              void* d_out, int out_size, void* d_ws, size_t ws_size,
                              hipStream_t stream) {
    const float* x      = (const float*)d_in[0];
    const int*   ei     = (const int*)  d_in[1];
    const int*   batch  = (const int*)  d_in[2];
    const float* lin0_w = (const float*)d_in[3];
    const float* lin0_b = (const float*)d_in[4];
    const float* nn1_w  = (const float*)d_in[5];
    const float* nn1_b  = (const float*)d_in[6];
    const float* nn2_w  = (const float*)d_in[7];
    const float* nn2_b  = (const float*)d_in[8];
    const float* conv_b = (const float*)d_in[9];
    const float* gwih   = (const float*)d_in[10];
    const float* gwhh   = (const float*)d_in[11];
    const float* gbih   = (const float*)d_in[12];
    const float* gbhh   = (const float*)d_in[13];
    const float* lwih   = (const float*)d_in[14];
    const float* lwhh   = (const float*)d_in[15];
    const float* lbih   = (const float*)d_in[16];
    const float* lbhh   = (const float*)d_in[17];

    float* qstar = (float*)d_out;                 // [256*128]
    float* h     = (float*)d_out + NGB * 128;     // [N*64] == feat_map

    float* ws     = (float*)d_ws;
    float* W      = ws;                         // 4096
    float* agg    = ws + 4096;                  // N*64
    int*   rowptr = (int*)(agg + NN * 64);      // NN+1
    int*   curp   = rowptr + NN + 1;            // NN
    int*   adj    = curp + NN;                  // NE
    int*   degc   = adj + NE;                   // NN
    int*   bsum   = degc + NN;                  // 256 (>=SCB)
    int*   cnt    = bsum + 256;                 // 256
    int*   starts = cnt + 256;                  // 256
    float* hl     = (float*)(starts + 256);     // 256*64
    float* cl     = hl + NGB * 64;              // 256*64
    float* wihT   = cl + NGB * 64;              // 128*256
    float* whhT   = wihT + 128 * 256;           // 64*256
    unsigned int* P = (unsigned int*)(whhT + 64 * 256);  // 14336
    float* brz    = (float*)(P + 14336);        // 128

    hipMemsetAsync(degc, 0, NN * sizeof(int), stream);

    k_precompute_W<<<16, 256, 0, stream>>>(nn1_w, nn1_b, nn2_w, nn2_b, W);
    k_pack_mfma<<<56, 256, 0, stream>>>(W, gwih, gwhh, gbih, gbhh, P, brz);
    k_transpose_lstm<<<128, 256, 0, stream>>>(lwih, lwhh, wihT, whhT);
    k_degi<<<(NE + 255) / 256, 256, 0, stream>>>(ei, degc);
    k_bsum<<<SCB, 256, 0, stream>>>(degc, bsum);
    k_emit<<<SCB, 256, 0, stream>>>(degc, bsum, rowptr, curp);
    k_fill<<<(NE + 255) / 256, 256, 0, stream>>>(ei, curp, adj);
    k_bounds<<<1, 256, 0, stream>>>(batch, starts, cnt);
    k_lin0<<<512, 256, 0, stream>>>(x, lin0_w, lin0_b, h);

    for (int it = 0; it < 3; ++it) {
        k_gather<<<(NN * 16 + 255) / 256, 256, 0, stream>>>(rowptr, adj, h, agg);
        k_update<<<782, 256, 0, stream>>>(agg, rowptr, P, conv_b, brz, gbih, gbhh, h);
    }
    for (int st = 0; st < 3; ++st) {
        k_s2s<<<NGB, 1024, 0, stream>>>(h, starts, cnt, wihT, whhT, lbih, lbhh,
                                        hl, cl, qstar, st == 0 ? 1 : 0);
    }
}

// Round 14
// 250.570 us; speedup vs baseline: 1.5433x; 1.0786x over previous
//
#include <hip/hip_runtime.h>
#include <math.h>

#define NN 50000
#define NE 60000
#define FIN 32
#define DIM 64
#define NGB 256   // graphs in batch
#define SCB 196   // scan blocks: 196*256 = 50176 >= NN

typedef short s8v __attribute__((ext_vector_type(8)));
typedef float f4v __attribute__((ext_vector_type(4)));

__device__ __forceinline__ float rl(float v, int lane) {
    return __int_as_float(__builtin_amdgcn_readlane(__float_as_int(v), lane));
}
__device__ __forceinline__ float sigm(float x) { return 1.f / (1.f + expf(-x)); }

// pack two f32 as bf16 (RTN-even) into one u32: a -> low16, b -> high16
__device__ __forceinline__ unsigned int pk2(float a, float b) {
    unsigned int ua = __float_as_uint(a);
    unsigned int ub = __float_as_uint(b);
    ua = (ua + 0x7FFFu + ((ua >> 16) & 1u)) >> 16;
    ub = (ub + 0x7FFFu + ((ub >> 16) & 1u)) & 0xFFFF0000u;
    return ua | ub;
}
__device__ __forceinline__ unsigned short pk1(float a) {
    unsigned int ua = __float_as_uint(a);
    return (unsigned short)((ua + 0x7FFFu + ((ua >> 16) & 1u)) >> 16);
}
__device__ __forceinline__ s8v as_s8(uint4 u) {
    union { uint4 a; s8v b; } c; c.a = u; return c.b;
}

// ---------------- precompute: W[i*64+o] = (relu(nn1_w + nn1_b) @ nn2_w^T + nn2_b)
__global__ void k_precompute_W(const float* __restrict__ nn1_w, const float* __restrict__ nn1_b,
                               const float* __restrict__ nn2_w, const float* __restrict__ nn2_b,
                               float* __restrict__ W) {
    __shared__ float t[64];
    int tid = threadIdx.x;
    if (tid < 64) t[tid] = fmaxf(nn1_w[tid] + nn1_b[tid], 0.f);
    __syncthreads();
    int k = blockIdx.x * blockDim.x + tid;   // 0..4095
    float acc = nn2_b[k];
    #pragma unroll
    for (int j = 0; j < 64; ++j) acc += t[j] * nn2_w[k * 64 + j];
    W[k] = acc;
}

// ---------------- pack weights into MFMA B-fragment layouts (bf16, XOR-swizzled)
__global__ void k_pack_mfma(const float* __restrict__ W, const float* __restrict__ wih,
                            const float* __restrict__ whh, const float* __restrict__ bih,
                            const float* __restrict__ bhh, unsigned int* __restrict__ P,
                            float* __restrict__ brz) {
    int q = blockIdx.x * 256 + threadIdx.x;   // 56*256 = 14336
    if (q < 128) brz[q] = bih[q] + bhh[q];    // summed r,z biases
    if (q < 2048) {                           // WpA
        int byte = q * 4, col = byte >> 7, rem = byte & 127;
        int lin = rem ^ ((col & 7) << 4);
        int k0 = (lin >> 4) * 8 + ((lin >> 2) & 3) * 2;
        P[q] = pk2(W[k0 * 64 + col], W[(k0 + 1) * 64 + col]);
    } else if (q < 10240) {                   // B01 (K=128)
        int w = q - 2048, byte = w * 4, col = byte >> 8, rem = byte & 255;
        int lin = rem ^ ((col & 7) << 4);
        int k0 = (lin >> 4) * 8 + ((lin >> 2) & 3) * 2;
        int g = col >> 6, o = col & 63;
        int rowbase = (g * 64 + o) * 64;
        const float* src = (k0 >= 64) ? whh : wih;
        int kk = (k0 >= 64) ? k0 - 64 : k0;
        P[q] = pk2(src[rowbase + kk], src[rowbase + kk + 1]);
    } else if (q < 12288) {                   // BnI
        int w = q - 10240, byte = w * 4, col = byte >> 7, rem = byte & 127;
        int lin = rem ^ ((col & 7) << 4);
        int k0 = (lin >> 4) * 8 + ((lin >> 2) & 3) * 2;
        P[q] = pk2(wih[(128 + col) * 64 + k0], wih[(128 + col) * 64 + k0 + 1]);
    } else {                                  // BnH
        int w = q - 12288, byte = w * 4, col = byte >> 7, rem = byte & 127;
        int lin = rem ^ ((col & 7) << 4);
        int k0 = (lin >> 4) * 8 + ((lin >> 2) & 3) * 2;
        P[q] = pk2(whh[(128 + col) * 64 + k0], whh[(128 + col) * 64 + k0 + 1]);
    }
}

// ---------------- transpose LSTM weights for coalesced gate dots
__global__ void k_transpose_lstm(const float* __restrict__ wih, const float* __restrict__ whh,
                                 float* __restrict__ wihT, float* __restrict__ whhT) {
    int p = blockIdx.x * 256 + threadIdx.x;
    if (p < 256 * 128) { int o = p >> 7, k = p & 127; wihT[k * 256 + o] = wih[p]; }
    if (p < 256 * 64)  { int o = p >> 6, k = p & 63;  whhT[k * 256 + o] = whh[p]; }
}

// ---------------- int degree over dst
__global__ void k_degi(const int* __restrict__ ei, int* __restrict__ degc) {
    int i = blockIdx.x * 256 + threadIdx.x;
    if (i < NE) atomicAdd(&degc[ei[NE + i]], 1);
}

// ---------------- hierarchical scan, level 1: per-block sums of degc
__global__ void k_bsum(const int* __restrict__ degc, int* __restrict__ bsum) {
    __shared__ int red[256];
    int t = threadIdx.x;
    int idx = blockIdx.x * 256 + t;
    red[t] = (idx < NN) ? degc[idx] : 0;
    __syncthreads();
    for (int off = 128; off; off >>= 1) {
        if (t < off) red[t] += red[t + off];
        __syncthreads();
    }
    if (t == 0) bsum[blockIdx.x] = red[0];
}

// ---------------- hierarchical scan, level 2: block offset + local scan -> rowptr, cur
__global__ void k_emit(const int* __restrict__ degc, const int* __restrict__ bsum,
                       int* __restrict__ rowptr, int* __restrict__ cur) {
    __shared__ int bo[256];
    __shared__ int sc[256];
    int t = threadIdx.x;
    int idx = blockIdx.x * 256 + t;
    bo[t] = (t < blockIdx.x) ? bsum[t] : 0;   // blockIdx.x <= 195 < 256
    __syncthreads();
    for (int off = 128; off; off >>= 1) {
        if (t < off) bo[t] += bo[t + off];
        __syncthreads();
    }
    int boff = bo[0];
    int v = (idx < NN) ? degc[idx] : 0;
    sc[t] = v;
    __syncthreads();
    for (int off = 1; off < 256; off <<= 1) {   // inclusive scan
        int u = (t >= off) ? sc[t - off] : 0;
        __syncthreads();
        sc[t] += u;
        __syncthreads();
    }
    if (idx <= NN) {
        int excl = boff + sc[t] - v;   // for idx==NN: v=0, sc = block total -> grand total
        rowptr[idx] = excl;
        if (idx < NN) cur[idx] = excl;
    }
}

// ---------------- fill CSR adjacency: adj[pos] = src for each (src,dst) edge
__global__ void k_fill(const int* __restrict__ ei, int* __restrict__ cur,
                       int* __restrict__ adj) {
    int i = blockIdx.x * 256 + threadIdx.x;
    if (i < NE) {
        int s = ei[i], d = ei[NE + i];
        int pos = atomicAdd(&cur[d], 1);
        adj[pos] = s;
    }
}

// ---------------- per-graph starts/cnt via binary search on sorted batch (no atomics)
__global__ void k_bounds(const int* __restrict__ batch, int* __restrict__ starts,
                         int* __restrict__ cnt) {
    __shared__ int sLB[257];
    int b = threadIdx.x;   // 0..255
    int lo = 0, hi = NN;
    while (lo < hi) {      // lower_bound(batch, b)
        int mid = (lo + hi) >> 1;
        if (batch[mid] < b) lo = mid + 1; else hi = mid;
    }
    sLB[b] = lo;
    if (b == 0) sLB[256] = NN;
    __syncthreads();
    starts[b] = sLB[b];
    cnt[b] = sLB[b + 1] - sLB[b];
}

// ---------------- lin0: h = relu(x @ lin0_w^T + b); grid-stride, weights staged ONCE
__global__ void k_lin0(const float* __restrict__ x, const float* __restrict__ w,
                       const float* __restrict__ b, float* __restrict__ h) {
    __shared__ float wT[FIN * 64];   // wT[k*64+o] = w[o*32+k]
    int tid = threadIdx.x;
    for (int p = tid; p < FIN * 64; p += 256) {
        int k = p >> 6, o = p & 63;          // linear LDS write, strided L2-hit read
        wT[p] = w[o * FIN + k];
    }
    __syncthreads();
    int l = tid & 63;
    float bl = b[l];
    int wave = blockIdx.x * 4 + (tid >> 6);
    int nwaves = gridDim.x * 4;
    for (int n0 = wave * 2; n0 < NN; n0 += nwaves * 2) {   // NN even: both nodes valid
        float xv0 = x[n0 * FIN + (l & 31)];
        float xv1 = x[(n0 + 1) * FIN + (l & 31)];
        float a0 = bl, a1 = bl;
        #pragma unroll
        for (int k = 0; k < FIN; ++k) {
            float wk = wT[k * 64 + l];
            a0 += rl(xv0, k) * wk;
            a1 += rl(xv1, k) * wk;
        }
        h[n0 * 64 + l] = fmaxf(a0, 0.f);
        h[(n0 + 1) * 64 + l] = fmaxf(a1, 0.f);
    }
}

// ---------------- FUSED CSR-gather + MFMA conv(W) + GRU node update.
// Wave = 16 nodes, block = 4 waves. Reads hin, writes hout (ping-pong, race-free).
// Lane l gathers its own A-frag slice: node = nb+(l&15), floats {kq*8..+8, 32+kq*8..+8}.
__global__ void __launch_bounds__(256) k_update(
    const float* __restrict__ hin, const int* __restrict__ rowptr,
    const int* __restrict__ adj, const unsigned int* __restrict__ P,
    const float* __restrict__ conv_b, const float* __restrict__ brz,
    const float* __restrict__ bih, const float* __restrict__ bhh,
    float* __restrict__ hout) {
    __shared__ unsigned int L[16384];   // 64 KB
    int tid = threadIdx.x;
    #pragma unroll
    for (int p = 0; p < 14336; p += 256) L[p + tid] = P[p + tid];
    __syncthreads();

    int l = tid & 63;
    int w = tid >> 6;
    int nb = (blockIdx.x * 4 + w) * 16;
    if (nb >= NN) return;               // idle waves in last block (after barrier)
    int row = l & 15, kq = l >> 4;      // A/B frag: row/col = lane&15, k-chunk = lane>>4
    int node = nb + row;

    // ---- fused gather: sum h_in[src] over in-edges for this lane's 16-float slice
    int es = rowptr[node], ee = rowptr[node + 1];
    float g0x = 0.f, g0y = 0.f, g0z = 0.f, g0w = 0.f;
    float g1x = 0.f, g1y = 0.f, g1z = 0.f, g1w = 0.f;
    float g2x = 0.f, g2y = 0.f, g2z = 0.f, g2w = 0.f;
    float g3x = 0.f, g3y = 0.f, g3z = 0.f, g3w = 0.f;
    for (int k = es; k < ee; ++k) {
        int src = adj[k];
        const float4* hp0 = (const float4*)(hin + src * 64 + kq * 8);
        const float4* hp1 = (const float4*)(hin + src * 64 + 32 + kq * 8);
        float4 v0 = hp0[0], v1 = hp0[1], v2 = hp1[0], v3 = hp1[1];
        g0x += v0.x; g0y += v0.y; g0z += v0.z; g0w += v0.w;
        g1x += v1.x; g1y += v1.y; g1z += v1.z; g1w += v1.w;
        g2x += v2.x; g2y += v2.y; g2z += v2.z; g2w += v2.w;
        g3x += v3.x; g3y += v3.y; g3z += v3.z; g3w += v3.w;
    }
    float dv = (float)(ee - es);
    float inv = dv > 0.f ? 1.f / dv : 0.f;

    // ---- A-frags of agg_mean (bf16): kt=0 from g0/g1, kt=1 from g2/g3
    uint4 aA[2];
    aA[0].x = pk2(g0x * inv, g0y * inv);
    aA[0].y = pk2(g0z * inv, g0w * inv);
    aA[0].z = pk2(g1x * inv, g1y * inv);
    aA[0].w = pk2(g1z * inv, g1w * inv);
    aA[1].x = pk2(g2x * inv, g2y * inv);
    aA[1].y = pk2(g2z * inv, g2w * inv);
    aA[1].z = pk2(g3x * inv, g3y * inv);
    aA[1].w = pk2(g3z * inv, g3w * inv);

    // ---- stage A: m = relu(aggmean @ W + conv_b)
    f4v mC[4];
    #pragma unroll
    for (int ct = 0; ct < 4; ++ct) {
        f4v acc = {0.f, 0.f, 0.f, 0.f};
        int col = ct * 16 + row;
        #pragma unroll
        for (int kt = 0; kt < 2; ++kt) {
            int boff = col * 128 + ((kt * 64 + kq * 16) ^ ((col & 7) << 4));
            uint4 b = *(const uint4*)((const char*)L + boff);
            acc = __builtin_amdgcn_mfma_f32_16x16x32_bf16(as_s8(aA[kt]), as_s8(b), acc, 0, 0, 0);
        }
        mC[ct] = acc;
    }

    // ---- transpose m to A-frag layout via per-wave LDS region (swizzled)
    int mbase = 57344 + w * 2048;
    #pragma unroll
    for (int ct = 0; ct < 4; ++ct) {
        int ch = ct * 16 + row;
        float cb = conv_b[ch];
        #pragma unroll
        for (int r = 0; r < 4; ++r) {
            float mval = fmaxf(mC[ct][r] + cb, 0.f);
            int nrow = kq * 4 + r;
            int off = mbase + ((nrow * 128 + ch * 2) ^ ((nrow & 7) << 4));
            *(unsigned short*)((char*)L + off) = pk1(mval);
        }
    }
    // same-wave DS ordering: reads below see the writes above (no block barrier needed)
    uint4 mA[2], hA[2];
    #pragma unroll
    for (int kt = 0; kt < 2; ++kt) {
        int off = mbase + ((row * 128 + kt * 64 + kq * 16) ^ ((row & 7) << 4));
        mA[kt] = *(const uint4*)((const char*)L + off);
        const float4* hs = (const float4*)(hin + node * 64 + kt * 32 + kq * 8);
        float4 y0 = hs[0], y1 = hs[1];
        hA[kt].x = pk2(y0.x, y0.y);
        hA[kt].y = pk2(y0.z, y0.w);
        hA[kt].z = pk2(y1.x, y1.y);
        hA[kt].w = pk2(y1.z, y1.w);
    }

    // ---- gates r,z: [m|h](16x128) @ B01(128x128)
    f4v g01[8];
    #pragma unroll
    for (int ct = 0; ct < 8; ++ct) {
        f4v acc = {0.f, 0.f, 0.f, 0.f};
        int col = ct * 16 + row;
        #pragma unroll
        for (int kt = 0; kt < 4; ++kt) {
            uint4 a = (kt < 2) ? mA[kt] : hA[kt - 2];
            int boff = 8192 + col * 256 + ((kt * 64 + kq * 16) ^ ((col & 7) << 4));
            uint4 b = *(const uint4*)((const char*)L + boff);
            acc = __builtin_amdgcn_mfma_f32_16x16x32_bf16(as_s8(a), as_s8(b), acc, 0, 0, 0);
        }
        g01[ct] = acc;
    }
    // ---- i_n = m @ wih_n^T ; h_n = h @ whh_n^T
    f4v gin[4], ghn[4];
    #pragma unroll
    for (int ct = 0; ct < 4; ++ct) {
        f4v ai = {0.f, 0.f, 0.f, 0.f}, ah = {0.f, 0.f, 0.f, 0.f};
        int col = ct * 16 + row;
        #pragma unroll
        for (int kt = 0; kt < 2; ++kt) {
            int swz = (kt * 64 + kq * 16) ^ ((col & 7) << 4);
            uint4 bi = *(const uint4*)((const char*)L + 40960 + col * 128 + swz);
            uint4 bh = *(const uint4*)((const char*)L + 49152 + col * 128 + swz);
            ai = __builtin_amdgcn_mfma_f32_16x16x32_bf16(as_s8(mA[kt]), as_s8(bi), ai, 0, 0, 0);
            ah = __builtin_amdgcn_mfma_f32_16x16x32_bf16(as_s8(hA[kt]), as_s8(bh), ah, 0, 0, 0);
        }
        gin[ct] = ai; ghn[ct] = ah;
    }

    // ---- epilogue: GRU cell in C-frag layout (col=lane&15, row=(lane>>4)*4+r)
    #pragma unroll
    for (int ct = 0; ct < 4; ++ct) {
        int ch = ct * 16 + row;
        float br = brz[ch], bz = brz[64 + ch];
        float bin = bih[128 + ch], bhn = bhh[128 + ch];
        #pragma unroll
        for (int r = 0; r < 4; ++r) {
            int n2 = nb + kq * 4 + r;
            float rg = sigm(g01[ct][r] + br);
            float zg = sigm(g01[4 + ct][r] + bz);
            float ng = tanhf(gin[ct][r] + bin + rg * (ghn[ct][r] + bhn));
            float hold = hin[n2 * 64 + ch];
            hout[n2 * 64 + ch] = (1.f - zg) * ng + zg * hold;
        }
    }
}

// ---------------- fused Set2Set step: LSTM + ONLINE segment softmax + weighted sum.
__global__ void __launch_bounds__(1024) k_s2s(
    const float* __restrict__ h, const int* __restrict__ starts,
    const int* __restrict__ cnt, const float* __restrict__ wihT,
    const float* __restrict__ whhT, const float* __restrict__ bih,
    const float* __restrict__ bhh, float* __restrict__ hl,
    float* __restrict__ cl, float* __restrict__ qstar, int first) {
    __shared__ float ga[256];
    __shared__ float hlv[64];
    __shared__ float mw[16], ssw[16];
    __shared__ float accw[16][64];
    int b = blockIdx.x, tid = threadIdx.x, w = tid >> 6, l = tid & 63;

    if (first) {
        if (tid < 64) {   // q_star = 0, hl = 0, cl = 0 -> gates are biases only
            float ig = sigm(bih[tid] + bhh[tid]);
            float gg = tanhf(bih[128 + tid] + bhh[128 + tid]);
            float og = sigm(bih[192 + tid] + bhh[192 + tid]);
            float c = ig * gg;
            cl[b * 64 + tid] = c;
            float hh = og * tanhf(c);
            hl[b * 64 + tid] = hh;
            hlv[tid] = hh;
        }
    } else {
        if (tid < 256) {
            const float* qs = qstar + b * 128;
            const float* hb = hl + b * 64;
            float a = bih[tid] + bhh[tid];
            for (int k = 0; k < 128; ++k) a += qs[k] * wihT[k * 256 + tid];
            for (int k = 0; k < 64; ++k)  a += hb[k] * whhT[k * 256 + tid];
            ga[tid] = a;
        }
        __syncthreads();
        if (tid < 64) {
            float c = sigm(ga[64 + tid]) * cl[b * 64 + tid] + sigm(ga[tid]) * tanhf(ga[128 + tid]);
            cl[b * 64 + tid] = c;
            float hh = sigm(ga[192 + tid]) * tanhf(c);
            hl[b * 64 + tid] = hh;
            hlv[tid] = hh;
        }
    }
    __syncthreads();

    int s = starts[b], c = cnt[b];
    float hld = hlv[l];
    float m = -1e30f, ss = 0.f, racc = 0.f;
    for (int i = w; i < c; i += 16) {
        float hv = h[(s + i) * 64 + l];
        float v = hv * hld;
        #pragma unroll
        for (int off = 32; off; off >>= 1) v += __shfl_xor(v, off, 64);
        float nm = fmaxf(m, v);
        float scale = expf(m - nm);     // 0 on first hit, 1 if no new max
        float p = expf(v - nm);
        ss = ss * scale + p;
        racc = racc * scale + p * hv;
        m = nm;
    }
    if (l == 0) { mw[w] = m; ssw[w] = ss; }
    accw[w][l] = racc;
    __syncthreads();
    if (tid < 64) {
        float M = -1e30f;
        #pragma unroll
        for (int q = 0; q < 16; ++q) M = fmaxf(M, mw[q]);
        float asum = 0.f, r = 0.f;
        #pragma unroll
        for (int q = 0; q < 16; ++q) {
            float f = expf(mw[q] - M);   // 0 for empty waves when M finite
            asum += ssw[q] * f;
            r += accw[q][tid] * f;
        }
        qstar[b * 128 + tid] = hlv[tid];
        qstar[b * 128 + 64 + tid] = r / (asum + 1e-16f);
    }
}

extern "C" void kernel_launch(void* const* d_in, const int* in_sizes, int n_in,
                              void* d_out, int out_size, void* d_ws, size_t ws_size,
                              hipStream_t stream) {
    const float* x      = (const float*)d_in[0];
    const int*   ei     = (const int*)  d_in[1];
    const int*   batch  = (const int*)  d_in[2];
    const float* lin0_w = (const float*)d_in[3];
    const float* lin0_b = (const float*)d_in[4];
    const float* nn1_w  = (const float*)d_in[5];
    const float* nn1_b  = (const float*)d_in[6];
    const float* nn2_w  = (const float*)d_in[7];
    const float* nn2_b  = (const float*)d_in[8];
    const float* conv_b = (const float*)d_in[9];
    const float* gwih   = (const float*)d_in[10];
    const float* gwhh   = (const float*)d_in[11];
    const float* gbih   = (const float*)d_in[12];
    const float* gbhh   = (const float*)d_in[13];
    const float* lwih   = (const float*)d_in[14];
    const float* lwhh   = (const float*)d_in[15];
    const float* lbih   = (const float*)d_in[16];
    const float* lbhh   = (const float*)d_in[17];

    float* qstar = (float*)d_out;                 // [256*128]
    float* hdo   = (float*)d_out + NGB * 128;     // [N*64] == feat_map (final)

    float* ws     = (float*)d_ws;
    float* W      = ws;                         // 4096
    float* hbuf   = ws + 4096;                  // N*64 ping-pong partner of hdo
    int*   rowptr = (int*)(hbuf + NN * 64);     // NN+1
    int*   curp   = rowptr + NN + 1;            // NN
    int*   adj    = curp + NN;                  // NE
    int*   degc   = adj + NE;                   // NN
    int*   bsum   = degc + NN;                  // 256 (>=SCB)
    int*   cnt    = bsum + 256;                 // 256
    int*   starts = cnt + 256;                  // 256
    float* hl     = (float*)(starts + 256);     // 256*64
    float* cl     = hl + NGB * 64;              // 256*64
    float* wihT   = cl + NGB * 64;              // 128*256
    float* whhT   = wihT + 128 * 256;           // 64*256
    unsigned int* P = (unsigned int*)(whhT + 64 * 256);  // 14336
    float* brz    = (float*)(P + 14336);        // 128

    hipMemsetAsync(degc, 0, NN * sizeof(int), stream);

    k_precompute_W<<<16, 256, 0, stream>>>(nn1_w, nn1_b, nn2_w, nn2_b, W);
    k_pack_mfma<<<56, 256, 0, stream>>>(W, gwih, gwhh, gbih, gbhh, P, brz);
    k_transpose_lstm<<<128, 256, 0, stream>>>(lwih, lwhh, wihT, whhT);
    k_degi<<<(NE + 255) / 256, 256, 0, stream>>>(ei, degc);
    k_bsum<<<SCB, 256, 0, stream>>>(degc, bsum);
    k_emit<<<SCB, 256, 0, stream>>>(degc, bsum, rowptr, curp);
    k_fill<<<(NE + 255) / 256, 256, 0, stream>>>(ei, curp, adj);
    k_bounds<<<1, 256, 0, stream>>>(batch, starts, cnt);
    k_lin0<<<512, 256, 0, stream>>>(x, lin0_w, lin0_b, hbuf);

    // ping-pong: hbuf -> hdo -> hbuf -> hdo  (final feat_map lands in d_out)
    k_update<<<782, 256, 0, stream>>>(hbuf, rowptr, adj, P, conv_b, brz, gbih, gbhh, hdo);
    k_update<<<782, 256, 0, stream>>>(hdo, rowptr, adj, P, conv_b, brz, gbih, gbhh, hbuf);
    k_update<<<782, 256, 0, stream>>>(hbuf, rowptr, adj, P, conv_b, brz, gbih, gbhh, hdo);

    for (int st = 0; st < 3; ++st) {
        k_s2s<<<NGB, 1024, 0, stream>>>(hdo, starts, cnt, wihT, whhT, lbih, lbhh,
                                        hl, cl, qstar, st == 0 ? 1 : 0);
    }
}